// Round 10
// baseline (555.491 us; speedup 1.0000x reference)
//
#include <hip/hip_runtime.h>
#include <stdint.h>

// ---------------------------------------------------------------------------
// RichAttention: out = softmax(QK^T - w*cdist(coords)) @ V, attn also output.
// B=8, S=2048, H=768, fp32 in/out.
// R10 = R9 + G-trick done with proven bodies only:
//   scores = Xq.(Wq^T Wk).Xk^T + rowadd + coladd - w*dist
//   Removes Q/K projections (-116 GF), adds P = Xq.Gt^T (+58 GF) + tiny Gt.
//   k_scores8p unchanged except +ra/ca epilogue; V-path and PV unchanged.
// ---------------------------------------------------------------------------

typedef _Float16 half8 __attribute__((ext_vector_type(8)));
typedef _Float16 half4v __attribute__((ext_vector_type(4)));
typedef float f32x4 __attribute__((ext_vector_type(4)));

#define DEVI static __device__ __forceinline__

constexpr int B_ = 8, S_ = 2048, H_ = 768;
constexpr long NX = (long)B_ * S_ * H_;   // 12,582,912
constexpr long NW = (long)H_ * H_;        // 589,824
constexpr long ATT = (long)B_ * S_ * S_;  // 33,554,432

DEVI void glds16(const void* g, void* l) {
  __builtin_amdgcn_global_load_lds(
      (const __attribute__((address_space(1))) uint32_t*)g,
      (__attribute__((address_space(3))) uint32_t*)l, 16, 0, 0);
}

// Stage a [128][32]-fp16 tile (8KB). LDS slot (r,c) holds global chunk
// c ^ ((r>>1)&3). 256 threads x 2 units.
DEVI void stage_tile(const _Float16* gbase, int rowStride, _Float16* lds, int tid) {
#pragma unroll
  for (int seg = 0; seg < 2; ++seg) {
    int u = seg * 256 + tid;
    int r = u >> 2, c = u & 3;
    int sc = c ^ ((r >> 1) & 3);
    glds16(gbase + (long)r * rowStride + sc * 8, lds + ((u & ~63) << 3));
  }
}

DEVI half8 frag(const _Float16* lds, int m0, int lane) {
  int row = m0 + (lane & 15);
  int c = (lane >> 4) ^ ((row >> 1) & 3);
  return *(const half8*)(lds + row * 32 + c * 8);
}

// ---------------------------------------------------------------------------
// K0: split. Xq -> hi/lo (d_out), Xk -> hi/lo (WS), Xv -> hi (d_out);
// Wq,Wk -> hi/lo, Wv -> hi (d_out Wbase).
// ---------------------------------------------------------------------------
__global__ __launch_bounds__(256) void k_split(
    const float* __restrict__ xq, const float* __restrict__ xk,
    const float* __restrict__ xv, const float* __restrict__ wq,
    const float* __restrict__ wk, const float* __restrict__ wv,
    _Float16* __restrict__ xqh, _Float16* __restrict__ xkh,
    _Float16* __restrict__ xvh, _Float16* __restrict__ wb) {
  const long NX4 = NX / 4, NW4 = NW / 4, TOT = 3 * NX4 + 3 * NW4;
  for (long u = (long)blockIdx.x * blockDim.x + threadIdx.x; u < TOT;
       u += (long)gridDim.x * blockDim.x) {
    const float4* src;
    _Float16 *dh, *dl = nullptr;
    bool wantLo = true;
    long idx;
    if (u < 3 * NX4) {
      int z = (u >= 2 * NX4) ? 2 : (u >= NX4) ? 1 : 0;
      idx = u - (long)z * NX4;
      if (z == 0) { src = (const float4*)xq; dh = xqh; dl = xqh + NX; }
      else if (z == 1) { src = (const float4*)xk; dh = xkh; dl = xkh + NX; }
      else { src = (const float4*)xv; dh = xvh; wantLo = false; }
    } else {
      long t = u - 3 * NX4;
      int z = (t >= 2 * NW4) ? 2 : (t >= NW4) ? 1 : 0;
      idx = t - (long)z * NW4;
      if (z == 0) { src = (const float4*)wq; dh = wb; dl = wb + NW; }
      else if (z == 1) { src = (const float4*)wk; dh = wb + 2 * NW; dl = wb + 3 * NW; }
      else { src = (const float4*)wv; dh = wb + 4 * NW; wantLo = false; }
    }
    float4 x = src[idx];
    half4v hi, lo;
    hi[0] = (_Float16)x.x; lo[0] = (_Float16)(x.x - (float)hi[0]);
    hi[1] = (_Float16)x.y; lo[1] = (_Float16)(x.y - (float)hi[1]);
    hi[2] = (_Float16)x.z; lo[2] = (_Float16)(x.z - (float)hi[2]);
    hi[3] = (_Float16)x.w; lo[3] = (_Float16)(x.w - (float)hi[3]);
    *(half4v*)(dh + idx * 4) = hi;
    if (wantLo) *(half4v*)(dl + idx * 4) = lo;
  }
}

// ---------------------------------------------------------------------------
// K_tr: transpose 4 contiguous 768x768 fp16 matrices (WqH,WqL,WkH,WkL).
// [verbatim R3, proven]
// ---------------------------------------------------------------------------
__global__ __launch_bounds__(256) void k_tr(const _Float16* __restrict__ in,
                                            _Float16* __restrict__ out) {
  const int z = blockIdx.z;
  const _Float16* src = in + (long)z * NW;
  _Float16* dst = out + (long)z * NW;
  __shared__ _Float16 t[64][72];
  int r0 = blockIdx.y * 64, c0 = blockIdx.x * 64;
#pragma unroll
  for (int it = 0; it < 2; ++it) {
    int idx = it * 256 + threadIdx.x;
    int r = idx >> 3, ch = idx & 7;
    *(half8*)&t[r][ch * 8] = *(const half8*)(src + (long)(r0 + r) * H_ + c0 + ch * 8);
  }
  __syncthreads();
#pragma unroll
  for (int it = 0; it < 2; ++it) {
    int idx = it * 256 + threadIdx.x;
    int r = idx >> 3, ch = idx & 7;
    half8 v;
#pragma unroll
    for (int k = 0; k < 8; ++k) v[k] = t[ch * 8 + k][r];
    *(half8*)(dst + (long)(c0 + r) * H_ + r0 + ch * 8) = v;
  }
}

// ---------------------------------------------------------------------------
// K_gemm3: C = A.B^T 3-term split, 128^2, K=768, split-write Oh/Ol.
// [verbatim R3, proven] Used for Gt = WkT.(WqT)^T, grid (6,6).
// ---------------------------------------------------------------------------
__global__ __launch_bounds__(256, 2) void k_gemm3(
    const _Float16* __restrict__ Ah_, const _Float16* __restrict__ Al_,
    const _Float16* __restrict__ Bh_, const _Float16* __restrict__ Bl_,
    _Float16* __restrict__ Oh, _Float16* __restrict__ Ol) {
  const int nt = blockIdx.x, mt = blockIdx.y;
  const int tid = threadIdx.x;
  __shared__ _Float16 sm[2][4][4096];
  f32x4 acc[4][4] = {};
  const _Float16* Ah = Ah_ + (long)(mt * 128) * H_;
  const _Float16* Al = Al_ + (long)(mt * 128) * H_;
  const _Float16* Bh = Bh_ + (long)(nt * 128) * H_;
  const _Float16* Bl = Bl_ + (long)(nt * 128) * H_;

  stage_tile(Ah, H_, sm[0][0], tid);
  stage_tile(Bh, H_, sm[0][2], tid);
  stage_tile(Al, H_, sm[0][1], tid);
  stage_tile(Bl, H_, sm[0][3], tid);
  __syncthreads();

  const int lane = tid & 63, wid = tid >> 6;
  const int wm = (wid >> 1) * 64, wn = (wid & 1) * 64;

  int cur = 0;
  for (int kk = 0; kk < 24; ++kk) {
    if (kk + 1 < 24) {
      int o = (kk + 1) * 32;
      stage_tile(Ah + o, H_, sm[cur ^ 1][0], tid);
      stage_tile(Bh + o, H_, sm[cur ^ 1][2], tid);
      stage_tile(Al + o, H_, sm[cur ^ 1][1], tid);
      stage_tile(Bl + o, H_, sm[cur ^ 1][3], tid);
    }
    half8 ah[4], bh[4], al[4], bl[4];
#pragma unroll
    for (int i = 0; i < 4; ++i) {
      ah[i] = frag(sm[cur][0], wm + i * 16, lane);
      al[i] = frag(sm[cur][1], wm + i * 16, lane);
    }
#pragma unroll
    for (int j = 0; j < 4; ++j) {
      bh[j] = frag(sm[cur][2], wn + j * 16, lane);
      bl[j] = frag(sm[cur][3], wn + j * 16, lane);
    }
#pragma unroll
    for (int i = 0; i < 4; ++i)
#pragma unroll
      for (int j = 0; j < 4; ++j) {
        acc[i][j] = __builtin_amdgcn_mfma_f32_16x16x32_f16(ah[i], bh[j],
                                                           acc[i][j], 0, 0, 0);
        acc[i][j] = __builtin_amdgcn_mfma_f32_16x16x32_f16(ah[i], bl[j],
                                                           acc[i][j], 0, 0, 0);
        acc[i][j] = __builtin_amdgcn_mfma_f32_16x16x32_f16(al[i], bh[j],
                                                           acc[i][j], 0, 0, 0);
      }
    __syncthreads();
    cur ^= 1;
  }

#pragma unroll
  for (int i = 0; i < 4; ++i) {
    int m_t = wm + i * 16 + ((lane >> 4) << 2);
#pragma unroll
    for (int j = 0; j < 4; ++j) {
      int n_t = wn + j * 16 + (lane & 15);
      int gn = nt * 128 + n_t;
#pragma unroll
      for (int r = 0; r < 4; ++r) {
        long gm = (long)mt * 128 + m_t + r;
        float y = acc[i][j][r];
        _Float16 hi = (_Float16)y;
        Oh[gm * H_ + gn] = hi;
        Ol[gm * H_ + gn] = (_Float16)(y - (float)hi);
      }
    }
  }
}

// ---------------------------------------------------------------------------
// K_gemmPV: z=0: P = Xq.Gt^T (3-term, split-write Ph/Pl, no bias).
//           z=1: v = Xv.Wv^T + bv -> transposed vT (1-term).
// [old k_proj body, proven] Grid (6,128,2).
// ---------------------------------------------------------------------------
__global__ __launch_bounds__(256, 2) void k_gemmPV(
    const _Float16* __restrict__ xqh, const _Float16* __restrict__ xvh,
    const _Float16* __restrict__ gth, const _Float16* __restrict__ wvh,
    const float* __restrict__ bv, _Float16* __restrict__ Ph,
    _Float16* __restrict__ Pl, _Float16* __restrict__ vT) {
  const int nt = blockIdx.x, mt = blockIdx.y, z = blockIdx.z;
  const int tid = threadIdx.x;
  const bool full = (z == 0);
  const _Float16* Xh = full ? xqh : xvh;
  const _Float16* Xl = xqh + NX;  // only used when full
  const _Float16* Wh = full ? gth : wvh;
  const _Float16* Wl = gth + NW;  // only used when full

  __shared__ _Float16 sm[2][4][4096];
  f32x4 acc[4][4] = {};

  const _Float16* Ah = Xh + (long)(mt * 128) * H_;
  const _Float16* Al = Xl + (long)(mt * 128) * H_;
  const _Float16* Bh = Wh + (long)(nt * 128) * H_;
  const _Float16* Bl = Wl + (long)(nt * 128) * H_;

  stage_tile(Ah, H_, sm[0][0], tid);
  stage_tile(Bh, H_, sm[0][2], tid);
  if (full) {
    stage_tile(Al, H_, sm[0][1], tid);
    stage_tile(Bl, H_, sm[0][3], tid);
  }
  __syncthreads();

  const int lane = tid & 63, wid = tid >> 6;
  const int wm = (wid >> 1) * 64, wn = (wid & 1) * 64;

  int cur = 0;
  for (int kk = 0; kk < 24; ++kk) {
    if (kk + 1 < 24) {
      int o = (kk + 1) * 32;
      stage_tile(Ah + o, H_, sm[cur ^ 1][0], tid);
      stage_tile(Bh + o, H_, sm[cur ^ 1][2], tid);
      if (full) {
        stage_tile(Al + o, H_, sm[cur ^ 1][1], tid);
        stage_tile(Bl + o, H_, sm[cur ^ 1][3], tid);
      }
    }
    half8 ah[4], bh[4];
#pragma unroll
    for (int i = 0; i < 4; ++i) ah[i] = frag(sm[cur][0], wm + i * 16, lane);
#pragma unroll
    for (int j = 0; j < 4; ++j) bh[j] = frag(sm[cur][2], wn + j * 16, lane);
#pragma unroll
    for (int i = 0; i < 4; ++i)
#pragma unroll
      for (int j = 0; j < 4; ++j)
        acc[i][j] = __builtin_amdgcn_mfma_f32_16x16x32_f16(ah[i], bh[j],
                                                           acc[i][j], 0, 0, 0);
    if (full) {
      half8 al[4], bl[4];
#pragma unroll
      for (int i = 0; i < 4; ++i) al[i] = frag(sm[cur][1], wm + i * 16, lane);
#pragma unroll
      for (int j = 0; j < 4; ++j) bl[j] = frag(sm[cur][3], wn + j * 16, lane);
#pragma unroll
      for (int i = 0; i < 4; ++i)
#pragma unroll
        for (int j = 0; j < 4; ++j) {
          acc[i][j] = __builtin_amdgcn_mfma_f32_16x16x32_f16(ah[i], bl[j],
                                                             acc[i][j], 0, 0, 0);
          acc[i][j] = __builtin_amdgcn_mfma_f32_16x16x32_f16(al[i], bh[j],
                                                             acc[i][j], 0, 0, 0);
        }
    }
    __syncthreads();
    cur ^= 1;
  }

#pragma unroll
  for (int i = 0; i < 4; ++i) {
    int m_t = wm + i * 16 + ((lane >> 4) << 2);
#pragma unroll
    for (int j = 0; j < 4; ++j) {
      int n_t = wn + j * 16 + (lane & 15);
      int gn = nt * 128 + n_t;
      if (full) {
#pragma unroll
        for (int r = 0; r < 4; ++r) {
          long gm = (long)mt * 128 + m_t + r;
          float y = acc[i][j][r];
          _Float16 hi = (_Float16)y;
          Ph[gm * H_ + gn] = hi;
          Pl[gm * H_ + gn] = (_Float16)(y - (float)hi);
        }
      } else {
        float bs = bv[gn];
        int gmI = mt * 128 + m_t;
        int bb = gmI >> 11, t0 = gmI & 2047;
        half4v pk;
#pragma unroll
        for (int r = 0; r < 4; ++r) pk[r] = (_Float16)(acc[i][j][r] + bs);
        *(half4v*)&vT[((long)bb * H_ + gn) * S_ + t0] = pk;
      }
    }
  }
}

// ---------------------------------------------------------------------------
// K_uv: u = Wq^T*bk, vv = Wk^T*bq (coalesced: block owns 256 columns),
// cb = bq.bk. Grid (3,2).
// ---------------------------------------------------------------------------
__global__ __launch_bounds__(256) void k_uv(const float* __restrict__ wq,
                                            const float* __restrict__ wk,
                                            const float* __restrict__ bq,
                                            const float* __restrict__ bk,
                                            float* u, float* vv, float* cb) {
  int i = blockIdx.x * 256 + threadIdx.x;
  const float* W = (blockIdx.y == 0) ? wq : wk;
  const float* bvec = (blockIdx.y == 0) ? bk : bq;
  float a = 0;
  for (int j = 0; j < H_; ++j) a = fmaf(W[(long)j * H_ + i], bvec[j], a);
  ((blockIdx.y == 0) ? u : vv)[i] = a;
  if (blockIdx.x == 0 && blockIdx.y == 0 && threadIdx.x == 0) {
    float c = 0;
    for (int j = 0; j < H_; ++j) c += bq[j] * bk[j];
    cb[0] = c;
  }
}

// ---------------------------------------------------------------------------
// K_dot: dst[row] = dot(src[row,:768], vec) (+cb). [verbatim R3, proven]
// ---------------------------------------------------------------------------
__global__ __launch_bounds__(256) void k_dot(const float* __restrict__ src,
                                             const float* __restrict__ vec,
                                             const float* __restrict__ cb,
                                             float* __restrict__ dst, int addc) {
  int wid = threadIdx.x >> 6, lane = threadIdx.x & 63;
  long row = (long)blockIdx.x * 4 + wid;
  const float4* p = (const float4*)(src + row * H_);
  const float4* q = (const float4*)vec;
  float s = 0;
#pragma unroll
  for (int k = 0; k < 3; ++k) {
    float4 a = p[lane + k * 64], b = q[lane + k * 64];
    s += a.x * b.x + a.y * b.y + a.z * b.z + a.w * b.w;
  }
#pragma unroll
  for (int o = 32; o; o >>= 1) s += __shfl_xor(s, o);
  if (lane == 0) dst[row] = s + (addc ? cb[0] : 0.0f);
}

// ---------------------------------------------------------------------------
// K2: raw scores = P.Xk^T (3-term) - w*dist + ra + ca. 8-phase [R9-proven]
// + rowadd/coladd epilogue. XCD swizzle (one batch per XCD).
// ---------------------------------------------------------------------------
__global__ __launch_bounds__(512, 2) void k_scores8p(
    const _Float16* __restrict__ qh, const _Float16* __restrict__ ql,
    const _Float16* __restrict__ kh_, const _Float16* __restrict__ kl_,
    const float* __restrict__ coords, const float* __restrict__ sw,
    const float* __restrict__ rowadd, const float* __restrict__ coladd,
    float* __restrict__ attn) {
  int bid = blockIdx.x + 8 * blockIdx.y + 64 * blockIdx.z;
  int swz = (bid & 7) * 64 + (bid >> 3);
  const int nt = swz & 7, mt = (swz >> 3) & 7, b = swz >> 6;
  const int tid = threadIdx.x, lane = tid & 63, wid = tid >> 6;
  const int wr = wid >> 2, wc = wid & 3;

  __shared__ _Float16 lds[2][2][2][8192];
  __shared__ float cco[4][256];
  __shared__ float rca[2][256];

  if (tid < 256) {
    long gi = (long)b * S_ + mt * 256 + tid;
    cco[0][tid] = coords[gi * 2 + 0];
    cco[1][tid] = coords[gi * 2 + 1];
    rca[0][tid] = rowadd[gi];
  } else {
    int t = tid - 256;
    long gj = (long)b * S_ + nt * 256 + t;
    cco[2][t] = coords[gj * 2 + 0];
    cco[3][t] = coords[gj * 2 + 1];
    rca[1][t] = coladd[gj];
  }
  const float w = sw[0];

  const long aoff = ((long)b * S_ + mt * 256) * H_;
  const long boff = ((long)b * S_ + nt * 256) * H_;

  long goff[2];
  int loff[2];
#pragma unroll
  for (int seg = 0; seg < 2; ++seg) {
    int u = seg * 512 + tid;
    int r = u >> 2, c = u & 3;
    int sc = c ^ ((r >> 1) & 3);
    goff[seg] = (long)r * H_ + sc * 8;
    loff[seg] = (u & ~63) << 3;
  }

  f32x4 acc[8][4] = {};

  auto stage_half = [&](int h) {
    int th = h >> 2, kind = h & 3;
    int khf = kind >> 1, mx = kind & 1;
    int term = th % 3;
    long ko = (long)(th / 3) * 64 + khf * 32;
    const _Float16* src = mx ? ((term == 1 ? kl_ : kh_) + boff + ko)
                             : ((term == 2 ? ql : qh) + aoff + ko);
    _Float16* dst = &lds[th & 1][khf][mx][0];
    glds16(src + goff[0], dst + loff[0]);
    glds16(src + goff[1], dst + loff[1]);
  };

  half8 bf[4];

  auto phase = [&](int slot, int kh2, int mh, int hst, int vm) {
    const _Float16* A = &lds[slot][kh2][0][0];
    const _Float16* Bt = &lds[slot][kh2][1][0];
    half8 af[4];
    if (mh == 0) {
#pragma unroll
      for (int j = 0; j < 4; ++j) bf[j] = frag(Bt, wc * 64 + j * 16, lane);
    }
#pragma unroll
    for (int i = 0; i < 4; ++i)
      af[i] = frag(A, wr * 128 + mh * 64 + i * 16, lane);
    if (hst >= 0) stage_half(hst);
    if (vm == 6) asm volatile("s_waitcnt vmcnt(6)" ::: "memory");
    else if (vm == 0) asm volatile("s_waitcnt vmcnt(0)" ::: "memory");
    __builtin_amdgcn_s_barrier();
    asm volatile("s_waitcnt lgkmcnt(0)" ::: "memory");
    __builtin_amdgcn_sched_barrier(0);
    __builtin_amdgcn_s_setprio(1);
#pragma unroll
    for (int i = 0; i < 4; ++i)
#pragma unroll
      for (int j = 0; j < 4; ++j)
        acc[mh * 4 + i][j] = __builtin_amdgcn_mfma_f32_16x16x32_f16(
            af[i], bf[j], acc[mh * 4 + i][j], 0, 0, 0);
    __builtin_amdgcn_s_setprio(0);
    asm volatile("" ::: "memory");
    __builtin_amdgcn_s_barrier();
  };

#pragma unroll
  for (int h = 0; h < 7; ++h) stage_half(h);
  asm volatile("s_waitcnt vmcnt(6)" ::: "memory");
  __builtin_amdgcn_s_barrier();

#pragma unroll 1
  for (int t = 0; t < 34; ++t) {
    const int slot = t & 1, P = 4 * t;
    phase(slot, 0, 0, P + 7, -1);
    phase(slot, 0, 1, P + 8, -1);
    phase(slot, 1, 0, P + 9, -1);
    phase(slot, 1, 1, P + 10, 6);
  }
  phase(0, 0, 0, 143, -1);
  phase(0, 0, 1, -1, -1);
  phase(0, 1, 0, -1, -1);
  phase(0, 1, 1, -1, 0);
  phase(1, 0, 0, -1, -1);
  phase(1, 0, 1, -1, -1);
  phase(1, 1, 0, -1, -1);
  phase(1, 1, 1, -1, -1);

#pragma unroll
  for (int mi = 0; mi < 8; ++mi) {
    int m_t = wr * 128 + mi * 16 + ((lane >> 4) << 2);
#pragma unroll
    for (int j = 0; j < 4; ++j) {
      int n_t = wc * 64 + j * 16 + (lane & 15);
      float cjx = cco[2][n_t], cjy = cco[3][n_t];
      float ca = rca[1][n_t];
      long rowbase = ((long)b * S_ + mt * 256 + m_t) * S_ + nt * 256 + n_t;
#pragma unroll
      for (int r = 0; r < 4; ++r) {
        float dx = cco[0][m_t + r] - cjx;
        float dy = cco[1][m_t + r] - cjy;
        float d = sqrtf(fmaxf(fmaf(dx, dx, dy * dy), 1e-12f));
        attn[rowbase + (long)r * S_] =
            acc[mi][j][r] - w * d + rca[0][m_t + r] + ca;
      }
    }
  }
}

// ---------------------------------------------------------------------------
// K2b: row softmax in place (fp32) + normalized fp16 copy for k_pv16.
// ---------------------------------------------------------------------------
__global__ __launch_bounds__(256) void k_rowsoft(float* __restrict__ attn,
                                                 _Float16* __restrict__ a16) {
  const int wid = threadIdx.x >> 6, lane = threadIdx.x & 63;
  long row = (long)blockIdx.x * 4 + wid;
  float* p = attn + row * S_;
  _Float16* p16 = a16 + row * S_;
  float4 v[8];
#pragma unroll
  for (int i = 0; i < 8; ++i) v[i] = ((const float4*)p)[i * 64 + lane];
  float m = -3.4e38f;
#pragma unroll
  for (int i = 0; i < 8; ++i)
    m = fmaxf(m, fmaxf(fmaxf(v[i].x, v[i].y), fmaxf(v[i].z, v[i].w)));
#pragma unroll
  for (int o = 32; o > 0; o >>= 1) m = fmaxf(m, __shfl_xor(m, o));
  float l = 0.f;
#pragma unroll
  for (int i = 0; i < 8; ++i) {
    v[i].x = __expf(v[i].x - m);
    v[i].y = __expf(v[i].y - m);
    v[i].z = __expf(v[i].z - m);
    v[i].w = __expf(v[i].w - m);
    l += (v[i].x + v[i].y) + (v[i].z + v[i].w);
  }
#pragma unroll
  for (int o = 32; o > 0; o >>= 1) l += __shfl_xor(l, o);
  const float rl = 1.0f / l;
#pragma unroll
  for (int i = 0; i < 8; ++i) {
    v[i].x *= rl; v[i].y *= rl; v[i].z *= rl; v[i].w *= rl;
    ((float4*)p)[i * 64 + lane] = v[i];
    half4v h = {(_Float16)v[i].x, (_Float16)v[i].y, (_Float16)v[i].z,
                (_Float16)v[i].w};
    ((half4v*)p16)[i * 64 + lane] = h;
  }
}

// ---------------------------------------------------------------------------
// K3: out = a16 @ vT^T. [verbatim R9, proven, XCD swizzle]
// ---------------------------------------------------------------------------
__global__ __launch_bounds__(256, 2) void k_pv16(
    const _Float16* __restrict__ a16, const _Float16* __restrict__ vT,
    float* __restrict__ outp) {
  int bid = blockIdx.x + 6 * blockIdx.y + 96 * blockIdx.z;
  int swz = (bid & 7) * 96 + (bid >> 3);
  const int nt = swz % 6, mt = (swz / 6) & 15, b = swz / 96;
  const int tid = threadIdx.x, lane = tid & 63, wid = tid >> 6;
  const int wm = (wid >> 1) * 64, wn = (wid & 1) * 64;
  __shared__ _Float16 sm[2][2][4096];
  f32x4 acc[4][4] = {};
  const _Float16* Ab = a16 + ((long)b * S_ + mt * 128) * S_;
  const _Float16* Bb = vT + ((long)b * H_ + nt * 128) * S_;

  stage_tile(Ab, S_, sm[0][0], tid);
  stage_tile(Bb, S_, sm[0][1], tid);
  __syncthreads();

  int cur = 0;
  for (int kk = 0; kk < 64; ++kk) {
    if (kk + 1 < 64) {
      stage_tile(Ab + (kk + 1) * 32, S_, sm[cur ^ 1][0], tid);
      stage_tile(Bb + (kk + 1) * 32, S_, sm[cur ^ 1][1], tid);
    }
    half8 ah[4], bh[4];
#pragma unroll
    for (int i = 0; i < 4; ++i) ah[i] = frag(sm[cur][0], wm + i * 16, lane);
#pragma unroll
    for (int j = 0; j < 4; ++j) bh[j] = frag(sm[cur][1], wn + j * 16, lane);
#pragma unroll
    for (int i = 0; i < 4; ++i)
#pragma unroll
      for (int j = 0; j < 4; ++j)
        acc[i][j] = __builtin_amdgcn_mfma_f32_16x16x32_f16(ah[i], bh[j],
                                                           acc[i][j], 0, 0, 0);
    __syncthreads();
    cur ^= 1;
  }

#pragma unroll
  for (int i = 0; i < 4; ++i) {
    int m_t = wm + i * 16 + ((lane >> 4) << 2);
#pragma unroll
    for (int j = 0; j < 4; ++j) {
      int n_t = wn + j * 16 + (lane & 15);
      int h = nt * 128 + n_t;
      long rowbase = (long)b * S_ + mt * 128 + m_t;
#pragma unroll
      for (int r = 0; r < 4; ++r) outp[(rowbase + r) * H_ + h] = acc[i][j][r];
    }
  }
}

// ---------------------------------------------------------------------------
extern "C" void kernel_launch(void* const* d_in, const int* in_sizes, int n_in,
                              void* d_out, int out_size, void* d_ws,
                              size_t ws_size, hipStream_t stream) {
  const float* xq = (const float*)d_in[0];
  const float* xk = (const float*)d_in[1];
  const float* xv = (const float*)d_in[2];
  const float* co = (const float*)d_in[3];
  const float* wq = (const float*)d_in[4];
  const float* bq = (const float*)d_in[5];
  const float* wk = (const float*)d_in[6];
  const float* bk = (const float*)d_in[7];
  const float* wv = (const float*)d_in[8];
  const float* bv = (const float*)d_in[9];
  const float* sw = (const float*)d_in[10];

  float* out = (float*)d_out;
  float* attn = out + NX;  // attn at d_out floats [NX, NX+ATT)

  // d_out scratch (all dead before k_scores8p writes attn):
  //   Xqh [0,NX), Xql [NX,2NX), Xvh [2NX,3NX),
  //   Wbase (WqH,WqL,WkH,WkL,WvH) [3NX, 3NX+5NW),
  //   WT (WqTH,WqTL,WkTH,WkTL)   [3NX+5NW, 3NX+9NW),
  //   GtH,GtL                    [3NX+9NW, 3NX+11NW).  Total 88.5MB < 184.5MB.
  _Float16* sc = (_Float16*)d_out;
  _Float16* Xqh = sc;
  _Float16* Xvh = sc + 2 * NX;
  _Float16* Wbase = sc + 3 * NX;
  _Float16* WT = Wbase + 5 * NW;
  _Float16* GtH = Wbase + 9 * NW;
  // extras (rowadd/coladd/u/vv/cb): d_out floats [0, 34K) -- written AFTER
  // k_gemmPV consumed Xqh; read by k_scores8p; dead before k_pv16.
  float* rowadd = out;
  float* coladd = out + 16384;
  float* u = out + 32768;
  float* vv = u + H_;
  float* cb = vv + H_;

  // ws (5*NX halfs = 125.8MB, same as R9): Ph,Pl,Xkh,Xkl,vT.
  // a16 (ATT halfs) aliases Ph..Xkh after k_scores8p.
  _Float16* Ph = (_Float16*)d_ws;
  _Float16* Pl = Ph + NX;
  _Float16* Xkh = Ph + 2 * NX;
  _Float16* vT = Ph + 4 * NX;
  _Float16* a16 = Ph;

  k_split<<<dim3(2048), 256, 0, stream>>>(xq, xk, xv, wq, wk, wv, Xqh, Xkh,
                                          Xvh, Wbase);
  k_tr<<<dim3(12, 12, 4), 256, 0, stream>>>(Wbase, WT);
  // Gt = WkT . (WqT)^T : A = WkT h/l, B = WqT h/l
  k_gemm3<<<dim3(6, 6), 256, 0, stream>>>(WT + 2 * NW, WT + 3 * NW, WT,
                                          WT + NW, GtH, GtH + NW);
  k_gemmPV<<<dim3(6, 128, 2), 256, 0, stream>>>(Xqh, Xvh, GtH, Wbase + 4 * NW,
                                                bv, Ph, Pl, vT);
  k_uv<<<dim3(3, 2), 256, 0, stream>>>(wq, wk, bq, bk, u, vv, cb);
  k_dot<<<dim3(4096), 256, 0, stream>>>(xq, u, cb, rowadd, 1);
  k_dot<<<dim3(4096), 256, 0, stream>>>(xk, vv, cb, coladd, 0);
  k_scores8p<<<dim3(8, 8, 8), 512, 0, stream>>>(Ph, Pl, Xkh, Xkh + NX, co, sw,
                                                rowadd, coladd, attn);
  k_rowsoft<<<dim3(4096), 256, 0, stream>>>(attn, a16);
  k_pv16<<<dim3(6, 16, 8), 256, 0, stream>>>(a16, vT, out);
}

// Round 11
// 481.686 us; speedup vs baseline: 1.1532x; 1.1532x over previous
//
#include <hip/hip_runtime.h>
#include <stdint.h>

// ---------------------------------------------------------------------------
// RichAttention: out = softmax(QK^T - w*cdist(coords)) @ V, attn also output.
// B=8, S=2048, H=768, fp32 in/out.
// R11 = R10 G-trick with the small-kernel overhead fixed:
//   - k_uv16: wave-per-row GEMV on fp16 WT (replaces 6-block k_uv, ~40->4us)
//   - ra/ca folded into k_rowsoft (BW-bound, free adds);
//     k_scores8p reverts to the R9-verbatim body (174.8us proven).
//   - all GEMM bodies verbatim R10 (passed).
// ---------------------------------------------------------------------------

typedef _Float16 half8 __attribute__((ext_vector_type(8)));
typedef _Float16 half4v __attribute__((ext_vector_type(4)));
typedef float f32x4 __attribute__((ext_vector_type(4)));

#define DEVI static __device__ __forceinline__

constexpr int B_ = 8, S_ = 2048, H_ = 768;
constexpr long NX = (long)B_ * S_ * H_;   // 12,582,912
constexpr long NW = (long)H_ * H_;        // 589,824
constexpr long ATT = (long)B_ * S_ * S_;  // 33,554,432

DEVI void glds16(const void* g, void* l) {
  __builtin_amdgcn_global_load_lds(
      (const __attribute__((address_space(1))) uint32_t*)g,
      (__attribute__((address_space(3))) uint32_t*)l, 16, 0, 0);
}

DEVI void stage_tile(const _Float16* gbase, int rowStride, _Float16* lds, int tid) {
#pragma unroll
  for (int seg = 0; seg < 2; ++seg) {
    int u = seg * 256 + tid;
    int r = u >> 2, c = u & 3;
    int sc = c ^ ((r >> 1) & 3);
    glds16(gbase + (long)r * rowStride + sc * 8, lds + ((u & ~63) << 3));
  }
}

DEVI half8 frag(const _Float16* lds, int m0, int lane) {
  int row = m0 + (lane & 15);
  int c = (lane >> 4) ^ ((row >> 1) & 3);
  return *(const half8*)(lds + row * 32 + c * 8);
}

// ---------------------------------------------------------------------------
// K0: split. Xq -> hi/lo (d_out), Xk -> hi/lo (WS), Xv -> hi (d_out);
// Wq,Wk -> hi/lo, Wv -> hi (d_out Wbase).  [verbatim R10, proven]
// ---------------------------------------------------------------------------
__global__ __launch_bounds__(256) void k_split(
    const float* __restrict__ xq, const float* __restrict__ xk,
    const float* __restrict__ xv, const float* __restrict__ wq,
    const float* __restrict__ wk, const float* __restrict__ wv,
    _Float16* __restrict__ xqh, _Float16* __restrict__ xkh,
    _Float16* __restrict__ xvh, _Float16* __restrict__ wb) {
  const long NX4 = NX / 4, NW4 = NW / 4, TOT = 3 * NX4 + 3 * NW4;
  for (long u = (long)blockIdx.x * blockDim.x + threadIdx.x; u < TOT;
       u += (long)gridDim.x * blockDim.x) {
    const float4* src;
    _Float16 *dh, *dl = nullptr;
    bool wantLo = true;
    long idx;
    if (u < 3 * NX4) {
      int z = (u >= 2 * NX4) ? 2 : (u >= NX4) ? 1 : 0;
      idx = u - (long)z * NX4;
      if (z == 0) { src = (const float4*)xq; dh = xqh; dl = xqh + NX; }
      else if (z == 1) { src = (const float4*)xk; dh = xkh; dl = xkh + NX; }
      else { src = (const float4*)xv; dh = xvh; wantLo = false; }
    } else {
      long t = u - 3 * NX4;
      int z = (t >= 2 * NW4) ? 2 : (t >= NW4) ? 1 : 0;
      idx = t - (long)z * NW4;
      if (z == 0) { src = (const float4*)wq; dh = wb; dl = wb + NW; }
      else if (z == 1) { src = (const float4*)wk; dh = wb + 2 * NW; dl = wb + 3 * NW; }
      else { src = (const float4*)wv; dh = wb + 4 * NW; wantLo = false; }
    }
    float4 x = src[idx];
    half4v hi, lo;
    hi[0] = (_Float16)x.x; lo[0] = (_Float16)(x.x - (float)hi[0]);
    hi[1] = (_Float16)x.y; lo[1] = (_Float16)(x.y - (float)hi[1]);
    hi[2] = (_Float16)x.z; lo[2] = (_Float16)(x.z - (float)hi[2]);
    hi[3] = (_Float16)x.w; lo[3] = (_Float16)(x.w - (float)hi[3]);
    *(half4v*)(dh + idx * 4) = hi;
    if (wantLo) *(half4v*)(dl + idx * 4) = lo;
  }
}

// ---------------------------------------------------------------------------
// K_tr: transpose 4 contiguous 768x768 fp16 matrices.  [verbatim, proven]
// ---------------------------------------------------------------------------
__global__ __launch_bounds__(256) void k_tr(const _Float16* __restrict__ in,
                                            _Float16* __restrict__ out) {
  const int z = blockIdx.z;
  const _Float16* src = in + (long)z * NW;
  _Float16* dst = out + (long)z * NW;
  __shared__ _Float16 t[64][72];
  int r0 = blockIdx.y * 64, c0 = blockIdx.x * 64;
#pragma unroll
  for (int it = 0; it < 2; ++it) {
    int idx = it * 256 + threadIdx.x;
    int r = idx >> 3, ch = idx & 7;
    *(half8*)&t[r][ch * 8] = *(const half8*)(src + (long)(r0 + r) * H_ + c0 + ch * 8);
  }
  __syncthreads();
#pragma unroll
  for (int it = 0; it < 2; ++it) {
    int idx = it * 256 + threadIdx.x;
    int r = idx >> 3, ch = idx & 7;
    half8 v;
#pragma unroll
    for (int k = 0; k < 8; ++k) v[k] = t[ch * 8 + k][r];
    *(half8*)(dst + (long)(c0 + r) * H_ + r0 + ch * 8) = v;
  }
}

// ---------------------------------------------------------------------------
// K_gemm3: C = A.B^T 3-term split, 128^2, K=768, split-write Oh/Ol.
// [verbatim, proven] Gt = WkT.(WqT)^T, grid (6,6).
// ---------------------------------------------------------------------------
__global__ __launch_bounds__(256, 2) void k_gemm3(
    const _Float16* __restrict__ Ah_, const _Float16* __restrict__ Al_,
    const _Float16* __restrict__ Bh_, const _Float16* __restrict__ Bl_,
    _Float16* __restrict__ Oh, _Float16* __restrict__ Ol) {
  const int nt = blockIdx.x, mt = blockIdx.y;
  const int tid = threadIdx.x;
  __shared__ _Float16 sm[2][4][4096];
  f32x4 acc[4][4] = {};
  const _Float16* Ah = Ah_ + (long)(mt * 128) * H_;
  const _Float16* Al = Al_ + (long)(mt * 128) * H_;
  const _Float16* Bh = Bh_ + (long)(nt * 128) * H_;
  const _Float16* Bl = Bl_ + (long)(nt * 128) * H_;

  stage_tile(Ah, H_, sm[0][0], tid);
  stage_tile(Bh, H_, sm[0][2], tid);
  stage_tile(Al, H_, sm[0][1], tid);
  stage_tile(Bl, H_, sm[0][3], tid);
  __syncthreads();

  const int lane = tid & 63, wid = tid >> 6;
  const int wm = (wid >> 1) * 64, wn = (wid & 1) * 64;

  int cur = 0;
  for (int kk = 0; kk < 24; ++kk) {
    if (kk + 1 < 24) {
      int o = (kk + 1) * 32;
      stage_tile(Ah + o, H_, sm[cur ^ 1][0], tid);
      stage_tile(Bh + o, H_, sm[cur ^ 1][2], tid);
      stage_tile(Al + o, H_, sm[cur ^ 1][1], tid);
      stage_tile(Bl + o, H_, sm[cur ^ 1][3], tid);
    }
    half8 ah[4], bh[4], al[4], bl[4];
#pragma unroll
    for (int i = 0; i < 4; ++i) {
      ah[i] = frag(sm[cur][0], wm + i * 16, lane);
      al[i] = frag(sm[cur][1], wm + i * 16, lane);
    }
#pragma unroll
    for (int j = 0; j < 4; ++j) {
      bh[j] = frag(sm[cur][2], wn + j * 16, lane);
      bl[j] = frag(sm[cur][3], wn + j * 16, lane);
    }
#pragma unroll
    for (int i = 0; i < 4; ++i)
#pragma unroll
      for (int j = 0; j < 4; ++j) {
        acc[i][j] = __builtin_amdgcn_mfma_f32_16x16x32_f16(ah[i], bh[j],
                                                           acc[i][j], 0, 0, 0);
        acc[i][j] = __builtin_amdgcn_mfma_f32_16x16x32_f16(ah[i], bl[j],
                                                           acc[i][j], 0, 0, 0);
        acc[i][j] = __builtin_amdgcn_mfma_f32_16x16x32_f16(al[i], bh[j],
                                                           acc[i][j], 0, 0, 0);
      }
    __syncthreads();
    cur ^= 1;
  }

#pragma unroll
  for (int i = 0; i < 4; ++i) {
    int m_t = wm + i * 16 + ((lane >> 4) << 2);
#pragma unroll
    for (int j = 0; j < 4; ++j) {
      int n_t = wn + j * 16 + (lane & 15);
      int gn = nt * 128 + n_t;
#pragma unroll
      for (int r = 0; r < 4; ++r) {
        long gm = (long)mt * 128 + m_t + r;
        float y = acc[i][j][r];
        _Float16 hi = (_Float16)y;
        Oh[gm * H_ + gn] = hi;
        Ol[gm * H_ + gn] = (_Float16)(y - (float)hi);
      }
    }
  }
}

// ---------------------------------------------------------------------------
// K_gemmPV: z=0: P = Xq.Gt^T (3-term, split-write). z=1: v = Xv.Wv^T + bv
// -> transposed vT (1-term).  [verbatim R10, proven] Grid (6,128,2).
// ---------------------------------------------------------------------------
__global__ __launch_bounds__(256, 2) void k_gemmPV(
    const _Float16* __restrict__ xqh, const _Float16* __restrict__ xvh,
    const _Float16* __restrict__ gth, const _Float16* __restrict__ wvh,
    const float* __restrict__ bv, _Float16* __restrict__ Ph,
    _Float16* __restrict__ Pl, _Float16* __restrict__ vT) {
  const int nt = blockIdx.x, mt = blockIdx.y, z = blockIdx.z;
  const int tid = threadIdx.x;
  const bool full = (z == 0);
  const _Float16* Xh = full ? xqh : xvh;
  const _Float16* Xl = xqh + NX;
  const _Float16* Wh = full ? gth : wvh;
  const _Float16* Wl = gth + NW;

  __shared__ _Float16 sm[2][4][4096];
  f32x4 acc[4][4] = {};

  const _Float16* Ah = Xh + (long)(mt * 128) * H_;
  const _Float16* Al = Xl + (long)(mt * 128) * H_;
  const _Float16* Bh = Wh + (long)(nt * 128) * H_;
  const _Float16* Bl = Wl + (long)(nt * 128) * H_;

  stage_tile(Ah, H_, sm[0][0], tid);
  stage_tile(Bh, H_, sm[0][2], tid);
  if (full) {
    stage_tile(Al, H_, sm[0][1], tid);
    stage_tile(Bl, H_, sm[0][3], tid);
  }
  __syncthreads();

  const int lane = tid & 63, wid = tid >> 6;
  const int wm = (wid >> 1) * 64, wn = (wid & 1) * 64;

  int cur = 0;
  for (int kk = 0; kk < 24; ++kk) {
    if (kk + 1 < 24) {
      int o = (kk + 1) * 32;
      stage_tile(Ah + o, H_, sm[cur ^ 1][0], tid);
      stage_tile(Bh + o, H_, sm[cur ^ 1][2], tid);
      if (full) {
        stage_tile(Al + o, H_, sm[cur ^ 1][1], tid);
        stage_tile(Bl + o, H_, sm[cur ^ 1][3], tid);
      }
    }
    half8 ah[4], bh[4];
#pragma unroll
    for (int i = 0; i < 4; ++i) ah[i] = frag(sm[cur][0], wm + i * 16, lane);
#pragma unroll
    for (int j = 0; j < 4; ++j) bh[j] = frag(sm[cur][2], wn + j * 16, lane);
#pragma unroll
    for (int i = 0; i < 4; ++i)
#pragma unroll
      for (int j = 0; j < 4; ++j)
        acc[i][j] = __builtin_amdgcn_mfma_f32_16x16x32_f16(ah[i], bh[j],
                                                           acc[i][j], 0, 0, 0);
    if (full) {
      half8 al[4], bl[4];
#pragma unroll
      for (int i = 0; i < 4; ++i) al[i] = frag(sm[cur][1], wm + i * 16, lane);
#pragma unroll
      for (int j = 0; j < 4; ++j) bl[j] = frag(sm[cur][3], wn + j * 16, lane);
#pragma unroll
      for (int i = 0; i < 4; ++i)
#pragma unroll
        for (int j = 0; j < 4; ++j) {
          acc[i][j] = __builtin_amdgcn_mfma_f32_16x16x32_f16(ah[i], bl[j],
                                                             acc[i][j], 0, 0, 0);
          acc[i][j] = __builtin_amdgcn_mfma_f32_16x16x32_f16(al[i], bh[j],
                                                             acc[i][j], 0, 0, 0);
        }
    }
    __syncthreads();
    cur ^= 1;
  }

#pragma unroll
  for (int i = 0; i < 4; ++i) {
    int m_t = wm + i * 16 + ((lane >> 4) << 2);
#pragma unroll
    for (int j = 0; j < 4; ++j) {
      int n_t = wn + j * 16 + (lane & 15);
      int gn = nt * 128 + n_t;
      if (full) {
#pragma unroll
        for (int r = 0; r < 4; ++r) {
          long gm = (long)mt * 128 + m_t + r;
          float y = acc[i][j][r];
          _Float16 hi = (_Float16)y;
          Ph[gm * H_ + gn] = hi;
          Pl[gm * H_ + gn] = (_Float16)(y - (float)hi);
        }
      } else {
        float bs = bv[gn];
        int gmI = mt * 128 + m_t;
        int bb = gmI >> 11, t0 = gmI & 2047;
        half4v pk;
#pragma unroll
        for (int r = 0; r < 4; ++r) pk[r] = (_Float16)(acc[i][j][r] + bs);
        *(half4v*)&vT[((long)bb * H_ + gn) * S_ + t0] = pk;
      }
    }
  }
}

// ---------------------------------------------------------------------------
// K_uv16: u[i] = WqT[i,:].bk, vv[i] = WkT[i,:].bq (wave per row, fp16 WT),
// cb = bq.bk. Grid (192,2), 4 waves/block. Runs AFTER gemmPV (u/vv/cb alias
// dead Xqh region).
// ---------------------------------------------------------------------------
__global__ __launch_bounds__(256) void k_uv16(const _Float16* __restrict__ WT,
                                              const float* __restrict__ bq,
                                              const float* __restrict__ bk,
                                              float* u, float* vv, float* cb) {
  const int wid = threadIdx.x >> 6, lane = threadIdx.x & 63;
  const int row = blockIdx.x * 4 + wid;  // 0..767
  const _Float16* h = WT + (blockIdx.y ? 2L * NW : 0L) + (long)row * H_;
  const _Float16* l = h + NW;
  const float* b = blockIdx.y ? bq : bk;
  float s = 0;
#pragma unroll
  for (int k = 0; k < 3; ++k) {
    half4v hv = ((const half4v*)h)[lane + k * 64];
    half4v lv = ((const half4v*)l)[lane + k * 64];
    float4 b4 = ((const float4*)b)[lane + k * 64];
    s += ((float)hv[0] + (float)lv[0]) * b4.x +
         ((float)hv[1] + (float)lv[1]) * b4.y +
         ((float)hv[2] + (float)lv[2]) * b4.z +
         ((float)hv[3] + (float)lv[3]) * b4.w;
  }
#pragma unroll
  for (int o = 32; o; o >>= 1) s += __shfl_xor(s, o);
  if (lane == 0) (blockIdx.y ? vv : u)[row] = s;
  // cb: one extra wave-dot in block (0,0), wave 0
  if (blockIdx.x == 0 && blockIdx.y == 0 && wid == 0) {
    float c = 0;
#pragma unroll
    for (int k = 0; k < 3; ++k) {
      float4 a4 = ((const float4*)bq)[lane + k * 64];
      float4 b4 = ((const float4*)bk)[lane + k * 64];
      c += a4.x * b4.x + a4.y * b4.y + a4.z * b4.z + a4.w * b4.w;
    }
#pragma unroll
    for (int o = 32; o; o >>= 1) c += __shfl_xor(c, o);
    if (lane == 0) cb[0] = c;
  }
}

// ---------------------------------------------------------------------------
// K_dot: dst[row] = dot(src[row,:768], vec) (+cb). [verbatim, proven]
// ---------------------------------------------------------------------------
__global__ __launch_bounds__(256) void k_dot(const float* __restrict__ src,
                                             const float* __restrict__ vec,
                                             const float* __restrict__ cb,
                                             float* __restrict__ dst, int addc) {
  int wid = threadIdx.x >> 6, lane = threadIdx.x & 63;
  long row = (long)blockIdx.x * 4 + wid;
  const float4* p = (const float4*)(src + row * H_);
  const float4* q = (const float4*)vec;
  float s = 0;
#pragma unroll
  for (int k = 0; k < 3; ++k) {
    float4 a = p[lane + k * 64], b = q[lane + k * 64];
    s += a.x * b.x + a.y * b.y + a.z * b.z + a.w * b.w;
  }
#pragma unroll
  for (int o = 32; o; o >>= 1) s += __shfl_xor(s, o);
  if (lane == 0) dst[row] = s + (addc ? cb[0] : 0.0f);
}

// ---------------------------------------------------------------------------
// K2: raw scores = P.Xk^T (3-term) - w*dist. [R9-VERBATIM 8-phase body,
// 174.8us proven; no ra/ca here]. XCD swizzle (one batch per XCD).
// ---------------------------------------------------------------------------
__global__ __launch_bounds__(512, 2) void k_scores8p(
    const _Float16* __restrict__ qh, const _Float16* __restrict__ ql,
    const _Float16* __restrict__ kh_, const _Float16* __restrict__ kl_,
    const float* __restrict__ coords, const float* __restrict__ sw,
    float* __restrict__ attn) {
  int bid = blockIdx.x + 8 * blockIdx.y + 64 * blockIdx.z;
  int swz = (bid & 7) * 64 + (bid >> 3);
  const int nt = swz & 7, mt = (swz >> 3) & 7, b = swz >> 6;
  const int tid = threadIdx.x, lane = tid & 63, wid = tid >> 6;
  const int wr = wid >> 2, wc = wid & 3;

  __shared__ _Float16 lds[2][2][2][8192];
  __shared__ float cco[4][256];

  if (tid < 256) {
    long gi = (long)b * S_ + mt * 256 + tid;
    cco[0][tid] = coords[gi * 2 + 0];
    cco[1][tid] = coords[gi * 2 + 1];
  } else {
    int t = tid - 256;
    long gj = (long)b * S_ + nt * 256 + t;
    cco[2][t] = coords[gj * 2 + 0];
    cco[3][t] = coords[gj * 2 + 1];
  }
  const float w = sw[0];

  const long aoff = ((long)b * S_ + mt * 256) * H_;
  const long boff = ((long)b * S_ + nt * 256) * H_;

  long goff[2];
  int loff[2];
#pragma unroll
  for (int seg = 0; seg < 2; ++seg) {
    int u = seg * 512 + tid;
    int r = u >> 2, c = u & 3;
    int sc = c ^ ((r >> 1) & 3);
    goff[seg] = (long)r * H_ + sc * 8;
    loff[seg] = (u & ~63) << 3;
  }

  f32x4 acc[8][4] = {};

  auto stage_half = [&](int h) {
    int th = h >> 2, kind = h & 3;
    int khf = kind >> 1, mx = kind & 1;
    int term = th % 3;
    long ko = (long)(th / 3) * 64 + khf * 32;
    const _Float16* src = mx ? ((term == 1 ? kl_ : kh_) + boff + ko)
                             : ((term == 2 ? ql : qh) + aoff + ko);
    _Float16* dst = &lds[th & 1][khf][mx][0];
    glds16(src + goff[0], dst + loff[0]);
    glds16(src + goff[1], dst + loff[1]);
  };

  half8 bf[4];

  auto phase = [&](int slot, int kh2, int mh, int hst, int vm) {
    const _Float16* A = &lds[slot][kh2][0][0];
    const _Float16* Bt = &lds[slot][kh2][1][0];
    half8 af[4];
    if (mh == 0) {
#pragma unroll
      for (int j = 0; j < 4; ++j) bf[j] = frag(Bt, wc * 64 + j * 16, lane);
    }
#pragma unroll
    for (int i = 0; i < 4; ++i)
      af[i] = frag(A, wr * 128 + mh * 64 + i * 16, lane);
    if (hst >= 0) stage_half(hst);
    if (vm == 6) asm volatile("s_waitcnt vmcnt(6)" ::: "memory");
    else if (vm == 0) asm volatile("s_waitcnt vmcnt(0)" ::: "memory");
    __builtin_amdgcn_s_barrier();
    asm volatile("s_waitcnt lgkmcnt(0)" ::: "memory");
    __builtin_amdgcn_sched_barrier(0);
    __builtin_amdgcn_s_setprio(1);
#pragma unroll
    for (int i = 0; i < 4; ++i)
#pragma unroll
      for (int j = 0; j < 4; ++j)
        acc[mh * 4 + i][j] = __builtin_amdgcn_mfma_f32_16x16x32_f16(
            af[i], bf[j], acc[mh * 4 + i][j], 0, 0, 0);
    __builtin_amdgcn_s_setprio(0);
    asm volatile("" ::: "memory");
    __builtin_amdgcn_s_barrier();
  };

#pragma unroll
  for (int h = 0; h < 7; ++h) stage_half(h);
  asm volatile("s_waitcnt vmcnt(6)" ::: "memory");
  __builtin_amdgcn_s_barrier();

#pragma unroll 1
  for (int t = 0; t < 34; ++t) {
    const int slot = t & 1, P = 4 * t;
    phase(slot, 0, 0, P + 7, -1);
    phase(slot, 0, 1, P + 8, -1);
    phase(slot, 1, 0, P + 9, -1);
    phase(slot, 1, 1, P + 10, 6);
  }
  phase(0, 0, 0, 143, -1);
  phase(0, 0, 1, -1, -1);
  phase(0, 1, 0, -1, -1);
  phase(0, 1, 1, -1, 0);
  phase(1, 0, 0, -1, -1);
  phase(1, 0, 1, -1, -1);
  phase(1, 1, 0, -1, -1);
  phase(1, 1, 1, -1, -1);

#pragma unroll
  for (int mi = 0; mi < 8; ++mi) {
    int m_t = wr * 128 + mi * 16 + ((lane >> 4) << 2);
#pragma unroll
    for (int j = 0; j < 4; ++j) {
      int n_t = wc * 64 + j * 16 + (lane & 15);
      float cjx = cco[2][n_t], cjy = cco[3][n_t];
      long rowbase = ((long)b * S_ + mt * 256 + m_t) * S_ + nt * 256 + n_t;
#pragma unroll
      for (int r = 0; r < 4; ++r) {
        float dx = cco[0][m_t + r] - cjx;
        float dy = cco[1][m_t + r] - cjy;
        float d = sqrtf(fmaxf(fmaf(dx, dx, dy * dy), 1e-12f));
        attn[rowbase + (long)r * S_] = acc[mi][j][r] - w * d;
      }
    }
  }
}

// ---------------------------------------------------------------------------
// K2b: row softmax in place + fp16 copy; ra/ca added here (BW-bound, free).
// ---------------------------------------------------------------------------
__global__ __launch_bounds__(256) void k_rowsoft(float* __restrict__ attn,
                                                 _Float16* __restrict__ a16,
                                                 const float* __restrict__ rowadd,
                                                 const float* __restrict__ coladd) {
  const int wid = threadIdx.x >> 6, lane = threadIdx.x & 63;
  long row = (long)blockIdx.x * 4 + wid;
  const int b = (int)(row >> 11);
  float* p = attn + row * S_;
  _Float16* p16 = a16 + row * S_;
  const float4* cav = (const float4*)(coladd + (long)b * S_);
  const float ra = rowadd[row];
  float4 v[8];
#pragma unroll
  for (int i = 0; i < 8; ++i) {
    v[i] = ((const float4*)p)[i * 64 + lane];
    float4 ca = cav[i * 64 + lane];
    v[i].x += ra + ca.x; v[i].y += ra + ca.y;
    v[i].z += ra + ca.z; v[i].w += ra + ca.w;
  }
  float m = -3.4e38f;
#pragma unroll
  for (int i = 0; i < 8; ++i)
    m = fmaxf(m, fmaxf(fmaxf(v[i].x, v[i].y), fmaxf(v[i].z, v[i].w)));
#pragma unroll
  for (int o = 32; o > 0; o >>= 1) m = fmaxf(m, __shfl_xor(m, o));
  float l = 0.f;
#pragma unroll
  for (int i = 0; i < 8; ++i) {
    v[i].x = __expf(v[i].x - m);
    v[i].y = __expf(v[i].y - m);
    v[i].z = __expf(v[i].z - m);
    v[i].w = __expf(v[i].w - m);
    l += (v[i].x + v[i].y) + (v[i].z + v[i].w);
  }
#pragma unroll
  for (int o = 32; o > 0; o >>= 1) l += __shfl_xor(l, o);
  const float rl = 1.0f / l;
#pragma unroll
  for (int i = 0; i < 8; ++i) {
    v[i].x *= rl; v[i].y *= rl; v[i].z *= rl; v[i].w *= rl;
    ((float4*)p)[i * 64 + lane] = v[i];
    half4v h = {(_Float16)v[i].x, (_Float16)v[i].y, (_Float16)v[i].z,
                (_Float16)v[i].w};
    ((half4v*)p16)[i * 64 + lane] = h;
  }
}

// ---------------------------------------------------------------------------
// K3: out = a16 @ vT^T. [verbatim R9, proven, XCD swizzle]
// ---------------------------------------------------------------------------
__global__ __launch_bounds__(256, 2) void k_pv16(
    const _Float16* __restrict__ a16, const _Float16* __restrict__ vT,
    float* __restrict__ outp) {
  int bid = blockIdx.x + 6 * blockIdx.y + 96 * blockIdx.z;
  int swz = (bid & 7) * 96 + (bid >> 3);
  const int nt = swz % 6, mt = (swz / 6) & 15, b = swz / 96;
  const int tid = threadIdx.x, lane = tid & 63, wid = tid >> 6;
  const int wm = (wid >> 1) * 64, wn = (wid & 1) * 64;
  __shared__ _Float16 sm[2][2][4096];
  f32x4 acc[4][4] = {};
  const _Float16* Ab = a16 + ((long)b * S_ + mt * 128) * S_;
  const _Float16* Bb = vT + ((long)b * H_ + nt * 128) * S_;

  stage_tile(Ab, S_, sm[0][0], tid);
  stage_tile(Bb, S_, sm[0][1], tid);
  __syncthreads();

  int cur = 0;
  for (int kk = 0; kk < 64; ++kk) {
    if (kk + 1 < 64) {
      stage_tile(Ab + (kk + 1) * 32, S_, sm[cur ^ 1][0], tid);
      stage_tile(Bb + (kk + 1) * 32, S_, sm[cur ^ 1][1], tid);
    }
    half8 ah[4], bh[4];
#pragma unroll
    for (int i = 0; i < 4; ++i) ah[i] = frag(sm[cur][0], wm + i * 16, lane);
#pragma unroll
    for (int j = 0; j < 4; ++j) bh[j] = frag(sm[cur][1], wn + j * 16, lane);
#pragma unroll
    for (int i = 0; i < 4; ++i)
#pragma unroll
      for (int j = 0; j < 4; ++j)
        acc[i][j] = __builtin_amdgcn_mfma_f32_16x16x32_f16(ah[i], bh[j],
                                                           acc[i][j], 0, 0, 0);
    __syncthreads();
    cur ^= 1;
  }

#pragma unroll
  for (int i = 0; i < 4; ++i) {
    int m_t = wm + i * 16 + ((lane >> 4) << 2);
#pragma unroll
    for (int j = 0; j < 4; ++j) {
      int n_t = wn + j * 16 + (lane & 15);
      int h = nt * 128 + n_t;
      long rowbase = (long)b * S_ + mt * 128 + m_t;
#pragma unroll
      for (int r = 0; r < 4; ++r) outp[(rowbase + r) * H_ + h] = acc[i][j][r];
    }
  }
}

// ---------------------------------------------------------------------------
extern "C" void kernel_launch(void* const* d_in, const int* in_sizes, int n_in,
                              void* d_out, int out_size, void* d_ws,
                              size_t ws_size, hipStream_t stream) {
  const float* xq = (const float*)d_in[0];
  const float* xk = (const float*)d_in[1];
  const float* xv = (const float*)d_in[2];
  const float* co = (const float*)d_in[3];
  const float* wq = (const float*)d_in[4];
  const float* bq = (const float*)d_in[5];
  const float* wk = (const float*)d_in[6];
  const float* bk = (const float*)d_in[7];
  const float* wv = (const float*)d_in[8];
  const float* bv = (const float*)d_in[9];
  const float* sw = (const float*)d_in[10];

  float* out = (float*)d_out;
  float* attn = out + NX;

  // d_out scratch (layout identical to R10, proven):
  _Float16* sc = (_Float16*)d_out;
  _Float16* Xqh = sc;
  _Float16* Xvh = sc + 2 * NX;
  _Float16* Wbase = sc + 3 * NX;
  _Float16* WT = Wbase + 5 * NW;
  _Float16* GtH = Wbase + 9 * NW;
  // extras in d_out floats [0,34K): written AFTER gemmPV consumed Xqh;
  // read by k_dot/k_rowsoft; dead before k_pv16 writes out.
  float* rowadd = out;
  float* coladd = out + 16384;
  float* u = out + 32768;
  float* vv = u + H_;
  float* cb = vv + H_;

  // ws: Ph,Pl,Xkh,Xkl,vT (5*NX halfs). a16 aliases Ph.. after k_scores8p.
  _Float16* Ph = (_Float16*)d_ws;
  _Float16* Pl = Ph + NX;
  _Float16* Xkh = Ph + 2 * NX;
  _Float16* vT = Ph + 4 * NX;
  _Float16* a16 = Ph;

  k_split<<<dim3(2048), 256, 0, stream>>>(xq, xk, xv, wq, wk, wv, Xqh, Xkh,
                                          Xvh, Wbase);
  k_tr<<<dim3(12, 12, 4), 256, 0, stream>>>(Wbase, WT);
  k_gemm3<<<dim3(6, 6), 256, 0, stream>>>(WT + 2 * NW, WT + 3 * NW, WT,
                                          WT + NW, GtH, GtH + NW);
  k_gemmPV<<<dim3(6, 128, 2), 256, 0, stream>>>(Xqh, Xvh, GtH, Wbase + 4 * NW,
                                                bv, Ph, Pl, vT);
  k_uv16<<<dim3(192, 2), 256, 0, stream>>>(WT, bq, bk, u, vv, cb);
  k_dot<<<dim3(4096), 256, 0, stream>>>(xq, u, cb, rowadd, 1);
  k_dot<<<dim3(4096), 256, 0, stream>>>(xk, vv, cb, coladd, 0);
  k_scores8p<<<dim3(8, 8, 8), 512, 0, stream>>>(Ph, Pl, Xkh, Xkh + NX, co, sw,
                                                attn);
  k_rowsoft<<<dim3(4096), 256, 0, stream>>>(attn, a16, rowadd, coladd);
  k_pv16<<<dim3(6, 16, 8), 256, 0, stream>>>(a16, vT, out);
}